// Round 5
// baseline (341.254 us; speedup 1.0000x reference)
//
#include <hip/hip_runtime.h>

#define EMBED 64
#define W1_STRIDE 132   // padded stride (floats): 16B-aligned rows, phase-uniform banks

// ---------------------------------------------------------------------------
// Fully fused: CSR-offset search + gather + segment-mean + concat +
// (x @ w1.T + b1) + relu.  One wave per row; 8 waves/block; single launch.
//
// CORRECTNESS INVARIANT (round-2/3 bug): every __shfl executes with all 64
// lanes active. Loops containing shuffles have WAVE-UNIFORM trip counts;
// ragged coverage is handled by predicating the accumulate, never the loop.
// The binary-search loop is divergent (trip count ±1 across lanes) but
// contains NO shuffles; __shfl extraction happens after reconvergence.
//
// Row bounds: start = lower_bound(seg, b), end = lower_bound(seg, b+1),
// computed lane-parallel with key = b + (lane & 1)  (seg_ids is sorted).
// Gather: per 64-edge chunk, ONE coalesced neigh_ids load; ids spread via
// __shfl; 4 independent float4 row-loads in flight per 16-lane sub-group.
// comb[wave] is same-wave-only LDS, handed off with __threadfence_block()
// (same-wave DS ops are HW-ordered; fence pins compiler order).
// __launch_bounds__(512, 8): 64-VGPR cap; 37 KB LDS -> 4 blocks/CU ->
// 32 waves/CU. grid 1024 * 8 = 8192 waves -> exactly 2 rows/wave.
// ---------------------------------------------------------------------------
__global__ __launch_bounds__(512, 8) void social_encoder_fused(
    const int*   __restrict__ nodes,
    const int*   __restrict__ neigh_ids,
    const int*   __restrict__ seg_ids,
    const float* __restrict__ features,
    const float* __restrict__ w1,
    const float* __restrict__ b1,
    float*       __restrict__ out,
    int B, int E)
{
    __shared__ float w1s[EMBED * W1_STRIDE];  // 33 KB; row j at w1s[j*132+c]
    __shared__ float comb[8][2 * EMBED];      // 4 KB; per-wave [self|mean-neigh]

    for (int i = threadIdx.x; i < EMBED * 2 * EMBED; i += 512)
        w1s[(i >> 7) * W1_STRIDE + (i & 127)] = w1[i];
    __syncthreads();   // only cross-wave barrier in the kernel

    const int wave = threadIdx.x >> 6;
    const int lane = threadIdx.x & 63;
    const int q    = lane & 15;   // float4 slot within a 64-float row
    const int sub  = lane >> 4;   // 4 concurrent edge slots
    const float bj = b1[lane];
    float* cwave = comb[wave];

    for (int b = blockIdx.x * 8 + wave; b < B; b += gridDim.x * 8) {
        // ---- CSR bounds via lower_bound over sorted seg_ids ----
        // lanes with (lane&1)==0 search key b, (lane&1)==1 search key b+1.
        // Divergent loop, no shuffles inside -> safe; reconverges at exit.
        const int key = b + (lane & 1);
        int lo = 0, hi = E;
        while (lo < hi) {
            const int mid = (lo + hi) >> 1;
            if (seg_ids[mid] < key) lo = mid + 1; else hi = mid;
        }
        const int start = __shfl(lo, 0, 64);   // full wave active
        const int end   = __shfl(lo, 1, 64);
        const int node  = nodes[b];

        // Self row: only sub-group 0 loads it (it alone stores it later).
        float4 sv = make_float4(0.f, 0.f, 0.f, 0.f);
        if (sub == 0)
            sv = ((const float4*)(features + ((size_t)node << 6)))[q];

        float4 acc = make_float4(0.f, 0.f, 0.f, 0.f);

        for (int chunk = start; chunk < end; chunk += 64) {   // uniform
            const int n = min(64, end - chunk);               // uniform
            int myid = 0;
            if (lane < n) myid = neigh_ids[chunk + lane];     // one coalesced load

            // ---- main: full 16-edge groups, UNIFORM trip count ----
            const int nfull = n & ~15;                        // uniform
            for (int base = 0; base < nfull; base += 16) {
                const int r0 = __shfl(myid, base + sub,      64);
                const int r1 = __shfl(myid, base + sub + 4,  64);
                const int r2 = __shfl(myid, base + sub + 8,  64);
                const int r3 = __shfl(myid, base + sub + 12, 64);
                const float4 v0 = ((const float4*)(features + ((size_t)r0 << 6)))[q];
                const float4 v1 = ((const float4*)(features + ((size_t)r1 << 6)))[q];
                const float4 v2 = ((const float4*)(features + ((size_t)r2 << 6)))[q];
                const float4 v3 = ((const float4*)(features + ((size_t)r3 << 6)))[q];
                acc.x += (v0.x + v1.x) + (v2.x + v3.x);
                acc.y += (v0.y + v1.y) + (v2.y + v3.y);
                acc.z += (v0.z + v1.z) + (v2.z + v3.z);
                acc.w += (v0.w + v1.w) + (v2.w + v3.w);
            }

            // ---- tail: r = n - nfull in [0,15], UNIFORM trip count ----
            const int r = n - nfull;                          // uniform
            const int tmax = (r + 3) >> 2;                    // uniform
            for (int t = 0; t < tmax; ++t) {
                const int src = nfull + sub + 4 * t;          // <= nfull+15 <= 63
                const int rid = __shfl(myid, src, 64);        // all lanes active
                const float4 v = ((const float4*)(features + ((size_t)rid << 6)))[q];
                if (src < n) {   // predicate the ACCUMULATE, not the loop
                    acc.x += v.x; acc.y += v.y; acc.z += v.z; acc.w += v.w;
                }
            }
        }

        // Reduce the 4 sub-groups (full wave active here).
        acc.x += __shfl_xor(acc.x, 16, 64); acc.x += __shfl_xor(acc.x, 32, 64);
        acc.y += __shfl_xor(acc.y, 16, 64); acc.y += __shfl_xor(acc.y, 32, 64);
        acc.z += __shfl_xor(acc.z, 16, 64); acc.z += __shfl_xor(acc.z, 32, 64);
        acc.w += __shfl_xor(acc.w, 16, 64); acc.w += __shfl_xor(acc.w, 32, 64);

        const float scale = 1.0f / fmaxf((float)(end - start), 1.0f);
        float4 nv;
        nv.x = acc.x * scale; nv.y = acc.y * scale;
        nv.z = acc.z * scale; nv.w = acc.w * scale;

        // comb = [self(16 float4) | neigh(16 float4)], slot = lane (0..31).
        // lanes 0-15 are sub 0 (hold sv); lanes 16-31 hold reduced nv.
        const float4 val = (lane < 16) ? sv : nv;
        if (lane < 32) ((float4*)cwave)[lane] = val;

        __threadfence_block();   // real fence; same-wave DS ops are HW-ordered

        float accd = bj;
        const float* wrow = &w1s[lane * W1_STRIDE];
        #pragma unroll 8
        for (int c = 0; c < 2 * EMBED; c += 4) {
            const float4 cv = *(const float4*)&cwave[c];   // broadcast read
            const float4 wv = *(const float4*)&wrow[c];    // ds_read_b128
            accd += cv.x * wv.x + cv.y * wv.y + cv.z * wv.z + cv.w * wv.w;
        }
        out[((size_t)b << 6) + lane] = fmaxf(accd, 0.0f);

        __threadfence_block();   // next iter's comb writes stay after these reads
    }
}

extern "C" void kernel_launch(void* const* d_in, const int* in_sizes, int n_in,
                              void* d_out, int out_size, void* d_ws, size_t ws_size,
                              hipStream_t stream) {
    const int*   nodes     = (const int*)d_in[0];
    const int*   neigh_ids = (const int*)d_in[1];
    const int*   seg_ids   = (const int*)d_in[2];
    const float* features  = (const float*)d_in[3];
    const float* w1        = (const float*)d_in[4];
    const float* b1        = (const float*)d_in[5];
    float*       out       = (float*)d_out;

    const int B = in_sizes[0];      // 16384
    const int E = in_sizes[1];      // 524288

    social_encoder_fused<<<1024, 512, 0, stream>>>(nodes, neigh_ids, seg_ids,
                                                   features, w1, b1, out, B, E);
}